// Round 8
// baseline (426.514 us; speedup 1.0000x reference)
//
#include <hip/hip_runtime.h>
#include <stdint.h>

typedef __attribute__((ext_vector_type(8))) short short8;
typedef __attribute__((ext_vector_type(8))) _Float16 half8;
typedef __attribute__((ext_vector_type(4))) float f32x4;

__device__ __forceinline__ unsigned short f2h(float x) {
  _Float16 h = (_Float16)x;
  return __builtin_bit_cast(unsigned short, h);
}
__device__ __forceinline__ float h2f(unsigned short u) {
  return (float)__builtin_bit_cast(_Float16, u);
}

#define GLOAD16(gsrc, ldst)                                              \
  __builtin_amdgcn_global_load_lds(                                      \
      (const __attribute__((address_space(1))) void*)(gsrc),             \
      (__attribute__((address_space(3))) void*)(ldst), 16, 0, 0)

#define VM(N) asm volatile("s_waitcnt vmcnt(" #N ")" ::: "memory")
#define BARSYNC __builtin_amdgcn_s_barrier()

// ---------- split fp32 -> (hi, lo) f16 ----------
__global__ __launch_bounds__(256) void split_pair_f16_kernel(
    const float* __restrict__ in, unsigned short* __restrict__ h,
    unsigned short* __restrict__ l) {
  size_t i = (size_t)blockIdx.x * 256 + threadIdx.x;
  float4 v = ((const float4*)in)[i];
  unsigned short h0 = f2h(v.x), h1 = f2h(v.y), h2 = f2h(v.z), h3 = f2h(v.w);
  ((ushort4*)h)[i] = make_ushort4(h0, h1, h2, h3);
  ((ushort4*)l)[i] = make_ushort4(f2h(v.x - h2f(h0)), f2h(v.y - h2f(h1)),
                                  f2h(v.z - h2f(h2)), f2h(v.w - h2f(h3)));
}

// ---------- transpose W [K][N] fp32 -> f16 [N][K] ----------
__global__ __launch_bounds__(256) void transpose_f16_kernel(
    const float* __restrict__ W, unsigned short* __restrict__ hT,
    int Kd, int Nd) {
  __shared__ float tile[32][33];
  int r = threadIdx.x >> 3;
  int c = (threadIdx.x & 7) * 4;
  int k0 = blockIdx.y * 32, n0 = blockIdx.x * 32;
  float4 v = *(const float4*)&W[(size_t)(k0 + r) * Nd + n0 + c];
  tile[r][c] = v.x; tile[r][c + 1] = v.y; tile[r][c + 2] = v.z; tile[r][c + 3] = v.w;
  __syncthreads();
  size_t o = (size_t)(n0 + r) * Kd + k0 + c;
  *(ushort4*)&hT[o] = make_ushort4(f2h(tile[c + 0][r]), f2h(tile[c + 1][r]),
                                   f2h(tile[c + 2][r]), f2h(tile[c + 3][r]));
}

// =====================================================================
// qkv_kernel: fused QKV projection. 2-term f16 NT GEMM, 256x256 tile,
// BK=32, tri-buffer 144KB (Ah 16KB | Al 16KB | B 16KB per tile),
// 6 slots/wave, stage 2 at p<3, VM(6)  -- gemm3-proven ledger.
// N=3072 = [q | k | v]; epilogue per n0-slab: q,k f16 [row][col],
// v f16 transposed [col][row] into vT.
// =====================================================================
__global__ __launch_bounds__(512, 2) void qkv_kernel(
    const unsigned short* __restrict__ Ah, const unsigned short* __restrict__ Al,
    const unsigned short* __restrict__ WT, const float* __restrict__ bq,
    const float* __restrict__ bk, const float* __restrict__ bv,
    unsigned short* __restrict__ qh, unsigned short* __restrict__ kh,
    unsigned short* __restrict__ vT) {
  __shared__ __align__(16) char smem[3 * 48 * 1024];
  constexpr int lda = 1024, ldb = 1024, K = 1024;
  const int t = threadIdx.x, wid = t >> 6, lane = t & 63;
  const int waveM = wid >> 2, waveN = wid & 3;
  const int lr0 = lane & 15, lk0 = (lane >> 4) * 8;
  const int m0 = blockIdx.y * 256, n0 = blockIdx.x * 256;

  const unsigned short* slot_src[6];
#pragma unroll
  for (int s = 0; s < 6; ++s) {
    int si = 6 * wid + s;
    const unsigned short* p;
    if (si < 16)      p = Ah + (size_t)(m0 + si * 16 + lr0) * lda + lk0;
    else if (si < 32) p = Al + (size_t)(m0 + (si - 16) * 16 + lr0) * lda + lk0;
    else              p = WT + (size_t)(n0 + (si - 32) * 16 + lr0) * ldb + lk0;
    slot_src[s] = p;
  }

  const int NTILES = K >> 5;  // 32
  f32x4 acc[8][4] = {};

#pragma unroll
  for (int tt = 0; tt < 2; ++tt)
#pragma unroll
    for (int s = 0; s < 6; ++s)
      GLOAD16(slot_src[s] + (size_t)tt * 32,
              smem + tt * 49152 + (6 * wid + s) * 1024);
  VM(6);
  BARSYNC;
  __builtin_amdgcn_sched_barrier(0);

  for (int tile = 0; tile < NTILES; ++tile) {
    const int cur = tile % 3, nxt = (tile + 2) % 3;
    const bool do_stage = (tile + 2) < NTILES;
    const char* cb = smem + cur * 49152;
    char* nb = smem + nxt * 49152;
    half8 bf[4];
#pragma unroll
    for (int p = 0; p < 4; ++p) {
      half8 ahf[2], alf[2];
#pragma unroll
      for (int i = 0; i < 2; ++i) {
        int mg = waveM * 8 + 2 * p + i;
        ahf[i] = *(const half8*)(cb + mg * 1024 + lane * 16);
        alf[i] = *(const half8*)(cb + 16384 + mg * 1024 + lane * 16);
      }
      if (p == 0) {
#pragma unroll
        for (int j = 0; j < 4; ++j) {
          int ng = waveN * 4 + j;
          bf[j] = *(const half8*)(cb + 32768 + ng * 1024 + lane * 16);
        }
      }
      if (do_stage && p < 3) {
#pragma unroll
        for (int s = 0; s < 2; ++s) {
          int slot = 2 * p + s;
          GLOAD16(slot_src[slot] + (size_t)(tile + 2) * 32,
                  nb + (6 * wid + slot) * 1024);
        }
      }
      __builtin_amdgcn_s_setprio(1);
#pragma unroll
      for (int i = 0; i < 2; ++i)
#pragma unroll
        for (int j = 0; j < 4; ++j) {
          f32x4 c = acc[2 * p + i][j];
          c = __builtin_amdgcn_mfma_f32_16x16x32_f16(ahf[i], bf[j], c, 0, 0, 0);
          c = __builtin_amdgcn_mfma_f32_16x16x32_f16(alf[i], bf[j], c, 0, 0, 0);
          acc[2 * p + i][j] = c;
        }
      __builtin_amdgcn_s_setprio(0);
      if (p < 3) __builtin_amdgcn_s_barrier();
    }
    if (tile + 1 < NTILES) {
      if (do_stage) VM(6); else VM(0);
      BARSYNC;
      __builtin_amdgcn_sched_barrier(0);
    }
  }

  const int or0 = (lane >> 4) * 4;
  const int slab = n0 >> 10;  // 0=q, 1=k, 2=v
#pragma unroll
  for (int mm = 0; mm < 8; ++mm)
#pragma unroll
    for (int j = 0; j < 4; ++j)
#pragma unroll
      for (int r = 0; r < 4; ++r) {
        int row = m0 + waveM * 128 + mm * 16 + or0 + r;
        int col = (n0 & 1023) + waveN * 64 + j * 16 + lr0;
        float x = acc[mm][j][r];
        if (slab == 0) {
          qh[(size_t)row * 1024 + col] = f2h(x + bq[col]);
        } else if (slab == 1) {
          kh[(size_t)row * 1024 + col] = f2h(x + bk[col]);
        } else {
          vT[(size_t)col * 8192 + row] = f2h(x + bv[col]);
        }
      }
}

// =====================================================================
// g1q: 1-term f16 NT GEMM (QK^T), 256x256 tile, BK=32, tri-buffer 96KB
// (A 16KB | B 16KB per tile), 4 slots/wave, stage 1/phase, VM(4).
// fp32 out. blockIdx.z strides.
// =====================================================================
__global__ __launch_bounds__(512, 2) void g1q_kernel(
    const unsigned short* __restrict__ Abase, size_t Astr, int lda,
    const unsigned short* __restrict__ Bbase, size_t Bstr, int ldb,
    float* __restrict__ outF, size_t Ostr, int ldo, int K) {
  __shared__ __align__(16) char smem[3 * 32 * 1024];
  const int t = threadIdx.x, wid = t >> 6, lane = t & 63;
  const int waveM = wid >> 2, waveN = wid & 3;
  const int lr0 = lane & 15, lk0 = (lane >> 4) * 8;
  const int m0 = blockIdx.y * 256, n0 = blockIdx.x * 256;
  const unsigned short* A = Abase + (size_t)blockIdx.z * Astr;
  const unsigned short* B = Bbase + (size_t)blockIdx.z * Bstr;
  float* out = outF + (size_t)blockIdx.z * Ostr;

  const unsigned short* slot_src[4];
#pragma unroll
  for (int s = 0; s < 4; ++s) {
    int si = 4 * wid + s;
    const unsigned short* p;
    if (si < 16) p = A + (size_t)(m0 + si * 16 + lr0) * lda + lk0;
    else         p = B + (size_t)(n0 + (si - 16) * 16 + lr0) * ldb + lk0;
    slot_src[s] = p;
  }

  const int NTILES = K >> 5;
  f32x4 acc[8][4] = {};

#pragma unroll
  for (int tt = 0; tt < 2; ++tt)
#pragma unroll
    for (int s = 0; s < 4; ++s)
      GLOAD16(slot_src[s] + (size_t)tt * 32,
              smem + tt * 32768 + (4 * wid + s) * 1024);
  VM(4);
  BARSYNC;
  __builtin_amdgcn_sched_barrier(0);

  for (int tile = 0; tile < NTILES; ++tile) {
    const int cur = tile % 3, nxt = (tile + 2) % 3;
    const bool do_stage = (tile + 2) < NTILES;
    const char* cb = smem + cur * 32768;
    char* nb = smem + nxt * 32768;
    half8 bf[4];
#pragma unroll
    for (int p = 0; p < 4; ++p) {
      half8 af[2];
#pragma unroll
      for (int i = 0; i < 2; ++i) {
        int mg = waveM * 8 + 2 * p + i;
        af[i] = *(const half8*)(cb + mg * 1024 + lane * 16);
      }
      if (p == 0) {
#pragma unroll
        for (int j = 0; j < 4; ++j) {
          int ng = waveN * 4 + j;
          bf[j] = *(const half8*)(cb + 16384 + ng * 1024 + lane * 16);
        }
      }
      if (do_stage)
        GLOAD16(slot_src[p] + (size_t)(tile + 2) * 32,
                nb + (4 * wid + p) * 1024);
      __builtin_amdgcn_s_setprio(1);
#pragma unroll
      for (int i = 0; i < 2; ++i)
#pragma unroll
        for (int j = 0; j < 4; ++j)
          acc[2 * p + i][j] = __builtin_amdgcn_mfma_f32_16x16x32_f16(
              af[i], bf[j], acc[2 * p + i][j], 0, 0, 0);
      __builtin_amdgcn_s_setprio(0);
      if (p < 3) __builtin_amdgcn_s_barrier();
    }
    if (tile + 1 < NTILES) {
      if (do_stage) VM(4); else VM(0);
      BARSYNC;
      __builtin_amdgcn_sched_barrier(0);
    }
  }

  const int or0 = (lane >> 4) * 4;
#pragma unroll
  for (int mm = 0; mm < 8; ++mm)
#pragma unroll
    for (int j = 0; j < 4; ++j)
#pragma unroll
      for (int r = 0; r < 4; ++r)
        out[(size_t)(m0 + waveM * 128 + mm * 16 + or0 + r) * ldo +
            (n0 + waveN * 64 + j * 16 + lr0)] = acc[mm][j][r];
}

// =====================================================================
// g1: 1-term f16 NT GEMM (PV), 256x128 tile, BK=64, tri-buffer 144KB,
// 6 slots/wave, VM(6) -- R6-proven, unchanged.
// =====================================================================
__global__ __launch_bounds__(512, 2) void g1_kernel(
    const unsigned short* __restrict__ Abase, size_t Astr, int lda,
    const unsigned short* __restrict__ Bbase, size_t Bstr, int ldb,
    float* __restrict__ outF, size_t Ostr, int ldo, int K) {
  __shared__ __align__(16) char smem[3 * 48 * 1024];
  const int t = threadIdx.x, wid = t >> 6, lane = t & 63;
  const int waveM = wid >> 2, waveN = wid & 3;
  const int lr0 = lane & 15, lk0 = (lane >> 4) * 8;
  const int m0 = blockIdx.y * 256, n0 = blockIdx.x * 128;
  const unsigned short* A = Abase + (size_t)blockIdx.z * Astr;
  const unsigned short* B = Bbase + (size_t)blockIdx.z * Bstr;
  float* out = outF + (size_t)blockIdx.z * Ostr;

  const unsigned short* slot_src[6];
#pragma unroll
  for (int s = 0; s < 6; ++s) {
    int si = 6 * wid + s;
    const unsigned short* p;
    if (si < 16)      p = A + (size_t)(m0 + si * 16 + lr0) * lda + lk0;
    else if (si < 32) p = A + (size_t)(m0 + (si - 16) * 16 + lr0) * lda + 32 + lk0;
    else if (si < 40) p = B + (size_t)(n0 + (si - 32) * 16 + lr0) * ldb + lk0;
    else              p = B + (size_t)(n0 + (si - 40) * 16 + lr0) * ldb + 32 + lk0;
    slot_src[s] = p;
  }

  const int NTILES = K >> 6;
  f32x4 acc[8][2] = {};

#pragma unroll
  for (int tt = 0; tt < 2; ++tt)
#pragma unroll
    for (int s = 0; s < 6; ++s)
      GLOAD16(slot_src[s] + (size_t)tt * 64,
              smem + tt * 49152 + (6 * wid + s) * 1024);
  VM(6);
  BARSYNC;
  __builtin_amdgcn_sched_barrier(0);

  for (int tile = 0; tile < NTILES; ++tile) {
    const int cur = tile % 3, nxt = (tile + 2) % 3;
    const bool do_stage = (tile + 2) < NTILES;
    const char* cb = smem + cur * 49152;
    char* nb = smem + nxt * 49152;
    half8 blo[2], bhi[2];
#pragma unroll
    for (int p = 0; p < 4; ++p) {
      half8 alo[2], ahi[2];
#pragma unroll
      for (int i = 0; i < 2; ++i) {
        int mg = waveM * 8 + 2 * p + i;
        alo[i] = *(const half8*)(cb + mg * 1024 + lane * 16);
        ahi[i] = *(const half8*)(cb + (16 + mg) * 1024 + lane * 16);
      }
      if (p == 0) {
#pragma unroll
        for (int j = 0; j < 2; ++j) {
          int ng = waveN * 2 + j;
          blo[j] = *(const half8*)(cb + (32 + ng) * 1024 + lane * 16);
          bhi[j] = *(const half8*)(cb + (40 + ng) * 1024 + lane * 16);
        }
      }
      if (do_stage && p < 3) {
#pragma unroll
        for (int s = 0; s < 2; ++s) {
          int slot = 2 * p + s;
          GLOAD16(slot_src[slot] + (size_t)(tile + 2) * 64,
                  nb + (6 * wid + slot) * 1024);
        }
      }
      __builtin_amdgcn_s_setprio(1);
#pragma unroll
      for (int i = 0; i < 2; ++i)
#pragma unroll
        for (int j = 0; j < 2; ++j) {
          f32x4 c = acc[2 * p + i][j];
          c = __builtin_amdgcn_mfma_f32_16x16x32_f16(alo[i], blo[j], c, 0, 0, 0);
          c = __builtin_amdgcn_mfma_f32_16x16x32_f16(ahi[i], bhi[j], c, 0, 0, 0);
          acc[2 * p + i][j] = c;
        }
      __builtin_amdgcn_s_setprio(0);
      if (p < 3) __builtin_amdgcn_s_barrier();
    }
    if (tile + 1 < NTILES) {
      if (do_stage) VM(6); else VM(0);
      BARSYNC;
      __builtin_amdgcn_sched_barrier(0);
    }
  }

  const int or0 = (lane >> 4) * 4;
#pragma unroll
  for (int mm = 0; mm < 8; ++mm)
#pragma unroll
    for (int j = 0; j < 2; ++j)
#pragma unroll
      for (int r = 0; r < 4; ++r)
        out[(size_t)(m0 + waveM * 128 + mm * 16 + or0 + r) * ldo +
            (n0 + waveN * 32 + j * 16 + lr0)] = acc[mm][j][r];
}

// ---------- row softmax: fp32 [4096] -> f16 probs (in-place capable) ----------
__global__ __launch_bounds__(256) void softmax_rows_kernel(
    const float* Sm, unsigned short* P, int ncol, int pld) {
  const int t = threadIdx.x;
  const float* srow = Sm + (size_t)blockIdx.x * ncol;
  float4 v[4];
  float m = -3.4e38f;
#pragma unroll
  for (int i = 0; i < 4; ++i) {
    v[i] = ((const float4*)srow)[t + 256 * i];
    m = fmaxf(m, fmaxf(fmaxf(v[i].x, v[i].y), fmaxf(v[i].z, v[i].w)));
  }
#pragma unroll
  for (int off = 32; off >= 1; off >>= 1) m = fmaxf(m, __shfl_down(m, off));
  __shared__ float redm[4];
  if ((t & 63) == 0) redm[t >> 6] = m;
  __syncthreads();
  m = fmaxf(fmaxf(redm[0], redm[1]), fmaxf(redm[2], redm[3]));
  float s = 0.f;
#pragma unroll
  for (int i = 0; i < 4; ++i) {
    v[i].x = __expf(v[i].x - m);
    v[i].y = __expf(v[i].y - m);
    v[i].z = __expf(v[i].z - m);
    v[i].w = __expf(v[i].w - m);
    s += v[i].x + v[i].y + v[i].z + v[i].w;
  }
#pragma unroll
  for (int off = 32; off >= 1; off >>= 1) s += __shfl_down(s, off);
  __shared__ float reds[4];
  if ((t & 63) == 0) reds[t >> 6] = s;
  __syncthreads();
  s = reds[0] + reds[1] + reds[2] + reds[3];
  float inv = 1.f / s;
  unsigned short* prow = P + (size_t)blockIdx.x * pld;
#pragma unroll
  for (int i = 0; i < 4; ++i) {
    ushort4 o = make_ushort4(f2h(v[i].x * inv), f2h(v[i].y * inv),
                             f2h(v[i].z * inv), f2h(v[i].w * inv));
    ((ushort4*)prow)[t + 256 * i] = o;
  }
}

extern "C" void kernel_launch(void* const* d_in, const int* in_sizes, int n_in,
                              void* d_out, int out_size, void* d_ws, size_t ws_size,
                              hipStream_t stream) {
  const float* hs = (const float*)d_in[0];
  const float* Wq = (const float*)d_in[1];
  const float* bq = (const float*)d_in[2];
  const float* Wk = (const float*)d_in[3];
  const float* bk = (const float*)d_in[4];
  const float* Wv = (const float*)d_in[5];
  const float* bv = (const float*)d_in[6];
  float* out = (float*)d_out;

  constexpr int Ss = 4096, Hh = 1024;
  constexpr int Mm = 8192;
  constexpr size_t TOK = (size_t)Ss * Hh;
  char* ws = (char*)d_ws;
  const size_t MB = 1024 * 1024;

  // live region [0,48MB): qh, kh (f16 [8192][1024]); vT (f16 [1024][8192])
  unsigned short* qh = (unsigned short*)(ws + 0 * MB);
  unsigned short* kh = (unsigned short*)(ws + 16 * MB);
  unsigned short* vT = (unsigned short*)(ws + 32 * MB);
  // region at +48MB: early = hs f16 splits (32MB) + WT f16 (6MB);
  // late = S slabs (big: 2x64MB, P f16 in-place strided)
  char* rb = ws + 48 * MB;
  unsigned short* hs_h = (unsigned short*)(rb + 0 * MB);
  unsigned short* hs_l = (unsigned short*)(rb + 16 * MB);
  unsigned short* WT = (unsigned short*)(rb + 32 * MB);  // [3072][1024]
  float* Sf = (float*)rb;

  const bool big = ws_size >= (size_t)176 * MB;

  // 1) splits; W -> [3072][1024] f16 (q | k | v)
  split_pair_f16_kernel<<<dim3(Mm * Hh / 1024), 256, 0, stream>>>(hs, hs_h, hs_l);
  transpose_f16_kernel<<<dim3(32, 32), 256, 0, stream>>>(Wq, WT, Hh, Hh);
  transpose_f16_kernel<<<dim3(32, 32), 256, 0, stream>>>(
      Wk, WT + (size_t)1024 * 1024, Hh, Hh);
  transpose_f16_kernel<<<dim3(32, 32), 256, 0, stream>>>(
      Wv, WT + (size_t)2048 * 1024, Hh, Hh);

  // 2) fused QKV projection (256x256 2-term): q,k f16; v f16 transposed
  qkv_kernel<<<dim3(12, 32), 512, 0, stream>>>(
      hs_h, hs_l, WT, bq, bk, bv, qh, kh, vT);

  if (big) {
    // 3) QK^T both batches (256x256 1-term) -> S slabs fp32
    g1q_kernel<<<dim3(16, 16, 2), 512, 0, stream>>>(
        qh, TOK, Hh, kh, TOK, Hh, Sf, (size_t)Ss * Ss, Ss, Hh);
    // 4) softmax all 8192 rows, in-place strided P f16 (pld = 8192 shorts)
    softmax_rows_kernel<<<dim3(2 * Ss), 256, 0, stream>>>(
        Sf, (unsigned short*)Sf, Ss, 2 * Ss);
    // 5) PV both batches (256x128 1-term)
    g1_kernel<<<dim3(8, 16, 2), 512, 0, stream>>>(
        (const unsigned short*)Sf, (size_t)Ss * 2 * Ss, 2 * Ss,
        vT, (size_t)Ss, Mm, out, TOK, Hh, Ss);
  } else {
    float* Sb = (float*)rb;
    unsigned short* Pb = (unsigned short*)(rb + 64 * MB);
    for (int b = 0; b < 2; ++b) {
      g1q_kernel<<<dim3(16, 16, 1), 512, 0, stream>>>(
          qh + b * TOK, 0, Hh, kh + b * TOK, 0, Hh, Sb, 0, Ss, Hh);
      softmax_rows_kernel<<<dim3(Ss), 256, 0, stream>>>(Sb, Pb, Ss, Ss);
      g1_kernel<<<dim3(8, 16, 1), 512, 0, stream>>>(
          Pb, 0, Ss, vT + (size_t)b * Ss, 0, Mm, out + b * TOK, 0, Hh, Ss);
    }
  }
}